// Round 1
// baseline (5109.631 us; speedup 1.0000x reference)
//
#include <hip/hip_runtime.h>
#include <hip/hip_bf16.h>
#include <cstdint>

#define LRELU_SLOPE 0.2f
constexpr int GN = 64;   // graphs

// ---------------------------------------------------------------- SGEMM (f32)
// C[M,N] = A[M,K] @ B[K,N].  BM=BN=64, BK=16, 256 threads, 4x4 microtile.
template<int BM, int BN, int BK>
__global__ __launch_bounds__(256)
void sgemm(const float* __restrict__ A, const float* __restrict__ B,
           float* __restrict__ C, int M, int N, int K) {
  __shared__ float As[BK][BM + 4];
  __shared__ float Bs[BK][BN];
  const int tid  = threadIdx.x;
  const int brow = blockIdx.y * BM;
  const int bcol = blockIdx.x * BN;
  const int tcol = (tid & 15) * 4;   // 0..60
  const int trow = (tid >> 4) * 4;   // 0..60
  const int am = tid >> 2;           // 0..63 : A row within tile
  const int ak = (tid & 3) * 4;      // 0,4,8,12
  const int bk = tid >> 4;           // 0..15 : B row within tile
  const int bc = (tid & 15) * 4;
  const int arow = brow + am;
  float acc[4][4] = {};
  for (int k0 = 0; k0 < K; k0 += BK) {
    float4 av = make_float4(0.f, 0.f, 0.f, 0.f);
    if (arow < M) av = *(const float4*)&A[(size_t)arow * K + k0 + ak];
    const float4 bv = *(const float4*)&B[(size_t)(k0 + bk) * N + bcol + bc];
    __syncthreads();
    As[ak + 0][am] = av.x; As[ak + 1][am] = av.y;
    As[ak + 2][am] = av.z; As[ak + 3][am] = av.w;
    *(float4*)&Bs[bk][bc] = bv;
    __syncthreads();
#pragma unroll
    for (int kk = 0; kk < BK; ++kk) {
      float ar[4], br[4];
#pragma unroll
      for (int i = 0; i < 4; ++i) ar[i] = As[kk][trow + i];
#pragma unroll
      for (int j = 0; j < 4; ++j) br[j] = Bs[kk][tcol + j];
#pragma unroll
      for (int i = 0; i < 4; ++i)
#pragma unroll
        for (int j = 0; j < 4; ++j)
          acc[i][j] = fmaf(ar[i], br[j], acc[i][j]);
    }
  }
#pragma unroll
  for (int i = 0; i < 4; ++i) {
    const int row = brow + trow + i;
    if (row < M)
      *(float4*)&C[(size_t)row * N + bcol + tcol] =
          make_float4(acc[i][0], acc[i][1], acc[i][2], acc[i][3]);
  }
}

// ------------------------------------------------- per-node attention logits
// block = H*C/4 threads, one node per block. Also zero-inits s and out row.
template<int H, int C>
__global__ __launch_bounds__(H * C / 4)
void node_att(const float* __restrict__ h, const float* __restrict__ a_src,
              const float* __restrict__ a_dst, float* __restrict__ es,
              float* __restrict__ ed, float* __restrict__ s,
              float* __restrict__ out) {
  const int n = blockIdx.x;
  const int t = threadIdx.x;
  const int c4 = t * 4;
  const int head = c4 / C;
  const float4 v  = *(const float4*)&h[(size_t)n * (H * C) + c4];
  const float4 as = *(const float4*)&a_src[c4];
  const float4 ad = *(const float4*)&a_dst[c4];
  float ps = v.x * as.x + v.y * as.y + v.z * as.z + v.w * as.w;
  float pd = v.x * ad.x + v.y * ad.y + v.z * ad.z + v.w * ad.w;
#pragma unroll
  for (int off = C / 8; off >= 1; off >>= 1) {
    ps += __shfl_xor(ps, off);
    pd += __shfl_xor(pd, off);
  }
  if ((t & (C / 4 - 1)) == 0) {
    es[n * H + head] = ps;
    ed[n * H + head] = pd;
  }
  if (t < H) s[n * H + t] = 0.f;
  *(float4*)&out[(size_t)n * (H * C) + c4] = make_float4(0.f, 0.f, 0.f, 0.f);
}

// ---------------------------------------------- edge softmax numerator + sum
// thread per (edge, head). No max-subtraction needed: |e| <~ 6 here.
template<int H>
__global__ __launch_bounds__(256)
void edge_exp(const int* __restrict__ ei, int E, int Etot,
              const float* __restrict__ es, const float* __restrict__ ed,
              float* __restrict__ ex, float* __restrict__ s) {
  const int t = blockIdx.x * 256 + threadIdx.x;
  if (t >= Etot * H) return;
  const int i = t / H, hh = t % H;
  const int sN = (i < E) ? ei[i]     : (i - E);
  const int dN = (i < E) ? ei[E + i] : (i - E);
  float e = es[sN * H + hh] + ed[dN * H + hh];
  e = (e > 0.f) ? e : LRELU_SLOPE * e;
  const float v = expf(e);
  ex[t] = v;
  unsafeAtomicAdd(&s[dN * H + hh], v);
}

// -------------------------------------------------- edge message aggregation
// block = H*C/4 threads, one edge per block; float4 gather + f32 atomics.
template<int H, int C>
__global__ __launch_bounds__(H * C / 4)
void edge_agg(const int* __restrict__ ei, int E,
              const float* __restrict__ h, const float* __restrict__ ex,
              const float* __restrict__ s, float* __restrict__ out) {
  const int i = blockIdx.x;
  const int t = threadIdx.x;
  const int sN = (i < E) ? ei[i]     : (i - E);
  const int dN = (i < E) ? ei[E + i] : (i - E);
  const int c4 = t * 4;
  const int head = c4 / C;
  const float alpha = ex[(size_t)i * H + head] / (s[dN * H + head] + 1e-16f);
  const float4 v = *(const float4*)&h[(size_t)sN * (H * C) + c4];
  float* o = &out[(size_t)dN * (H * C) + c4];
  unsafeAtomicAdd(o + 0, v.x * alpha);
  unsafeAtomicAdd(o + 1, v.y * alpha);
  unsafeAtomicAdd(o + 2, v.z * alpha);
  unsafeAtomicAdd(o + 3, v.w * alpha);
}

// -------------------------------------------------------- LayerNorm (+ReLU)
// block = D/4 threads (1 or 2 waves), one row per block, in place.
template<int D, bool RELU>
__global__ __launch_bounds__(D / 4)
void ln_kernel(float* __restrict__ x, const float* __restrict__ bias,
               const float* __restrict__ g, const float* __restrict__ b) {
  const int n = blockIdx.x;
  const int t = threadIdx.x;
  float4 v = *(float4*)&x[(size_t)n * D + t * 4];
  const float4 bb = *(const float4*)&bias[t * 4];
  v.x += bb.x; v.y += bb.y; v.z += bb.z; v.w += bb.w;
  float sum = v.x + v.y + v.z + v.w;
  float sq  = v.x * v.x + v.y * v.y + v.z * v.z + v.w * v.w;
#pragma unroll
  for (int off = 32; off >= 1; off >>= 1) {
    sum += __shfl_xor(sum, off);
    sq  += __shfl_xor(sq, off);
  }
  float tsum, tsq;
  if constexpr (D / 4 > 64) {
    __shared__ float red[2][2];
    const int wid = t >> 6;
    if ((t & 63) == 0) { red[wid][0] = sum; red[wid][1] = sq; }
    __syncthreads();
    tsum = red[0][0] + red[1][0];
    tsq  = red[0][1] + red[1][1];
  } else {
    tsum = sum; tsq = sq;
  }
  const float mu  = tsum / D;
  const float var = tsq / D - mu * mu;
  const float r   = rsqrtf(var + 1e-5f);
  const float4 gg  = *(const float4*)&g[t * 4];
  const float4 bl  = *(const float4*)&b[t * 4];
  float4 y;
  y.x = (v.x - mu) * r * gg.x + bl.x;
  y.y = (v.y - mu) * r * gg.y + bl.y;
  y.z = (v.z - mu) * r * gg.z + bl.z;
  y.w = (v.w - mu) * r * gg.w + bl.w;
  if constexpr (RELU) {
    y.x = fmaxf(y.x, 0.f); y.y = fmaxf(y.y, 0.f);
    y.z = fmaxf(y.z, 0.f); y.w = fmaxf(y.w, 0.f);
  }
  *(float4*)&x[(size_t)n * D + t * 4] = y;
}

// ---------------------------------------------------------- global mean pool
// 64 blocks (one per graph) x 256 threads; batch is sorted -> binary search.
__global__ __launch_bounds__(256)
void pool_kernel(const float* __restrict__ x, const int* __restrict__ batch,
                 float* __restrict__ out, int n_nodes) {
  const int g = blockIdx.x;
  const int t = threadIdx.x;
  int lo = 0, hi = n_nodes;
  while (lo < hi) { int mid = (lo + hi) >> 1; if (batch[mid] < g) lo = mid + 1; else hi = mid; }
  const int start = lo;
  hi = n_nodes;
  while (lo < hi) { int mid = (lo + hi) >> 1; if (batch[mid] < g + 1) lo = mid + 1; else hi = mid; }
  const int end = lo;
  float sum = 0.f;
  for (int r = start; r < end; ++r) sum += x[(size_t)r * 256 + t];
  out[g * 256 + t] = sum / fmaxf((float)(end - start), 1.f);
}

// ---------------------------------------------------------------------------
extern "C" void kernel_launch(void* const* d_in, const int* in_sizes, int n_in,
                              void* d_out, int out_size, void* d_ws, size_t ws_size,
                              hipStream_t stream) {
  const float* x    = (const float*)d_in[0];
  const int*   ei   = (const int*)d_in[1];
  const int*   batch= (const int*)d_in[2];
  const float* W1   = (const float*)d_in[3];
  const float* as1  = (const float*)d_in[4];
  const float* ad1  = (const float*)d_in[5];
  const float* b1   = (const float*)d_in[6];
  const float* g1   = (const float*)d_in[7];
  const float* be1  = (const float*)d_in[8];
  const float* W2   = (const float*)d_in[9];
  const float* as2  = (const float*)d_in[10];
  const float* ad2  = (const float*)d_in[11];
  const float* b2   = (const float*)d_in[12];
  const float* g2   = (const float*)d_in[13];
  const float* be2  = (const float*)d_in[14];

  const int N    = in_sizes[0] / 256;   // 50000
  const int E    = in_sizes[1] / 2;     // 400000
  const int Etot = E + N;               // self-loops appended

  float* ws   = (float*)d_ws;
  float* h1   = ws;                            // N*512
  float* out1 = h1   + (size_t)N * 512;        // N*512 (becomes x2)
  float* es1  = out1 + (size_t)N * 512;        // N*4
  float* ed1  = es1  + (size_t)N * 4;          // N*4
  float* s1   = ed1  + (size_t)N * 4;          // N*4
  float* ex1  = s1   + (size_t)N * 4;          // Etot*4
  // layer-2 buffers alias layer-1 regions that are dead by then
  float* h2   = h1;                            // N*256
  float* out2 = h1 + (size_t)N * 256;          // N*256
  float* es2 = es1; float* ed2 = ed1; float* s2 = s1; float* ex2 = ex1;

  // ---- layer 1: GATConv(256 -> 4x128) ----
  sgemm<64, 64, 16><<<dim3(512 / 64, (N + 63) / 64), 256, 0, stream>>>(
      x, W1, h1, N, 512, 256);
  node_att<4, 128><<<N, 128, 0, stream>>>(h1, as1, ad1, es1, ed1, s1, out1);
  edge_exp<4><<<(Etot * 4 + 255) / 256, 256, 0, stream>>>(ei, E, Etot, es1, ed1, ex1, s1);
  edge_agg<4, 128><<<Etot, 128, 0, stream>>>(ei, E, h1, ex1, s1, out1);
  ln_kernel<512, true><<<N, 128, 0, stream>>>(out1, b1, g1, be1);

  // ---- layer 2: GATConv(512 -> 1x256) ----
  sgemm<64, 64, 16><<<dim3(256 / 64, (N + 63) / 64), 256, 0, stream>>>(
      out1, W2, h2, N, 256, 512);
  node_att<1, 256><<<N, 64, 0, stream>>>(h2, as2, ad2, es2, ed2, s2, out2);
  edge_exp<1><<<(Etot + 255) / 256, 256, 0, stream>>>(ei, E, Etot, es2, ed2, ex2, s2);
  edge_agg<1, 256><<<Etot, 64, 0, stream>>>(ei, E, h2, ex2, s2, out2);
  ln_kernel<256, false><<<N, 64, 0, stream>>>(out2, b2, g2, be2);

  // ---- global mean pool ----
  pool_kernel<<<GN, 256, 0, stream>>>(out2, batch, (float*)d_out, N);
}

// Round 2
// 998.640 us; speedup vs baseline: 5.1166x; 5.1166x over previous
//
#include <hip/hip_runtime.h>
#include <hip/hip_bf16.h>
#include <cstdint>

#define LRELU_SLOPE 0.2f
constexpr int GN = 64;   // graphs

// ---------------------------------------------------------------- SGEMM (f32)
// C[M,N] = A[M,K] @ B[K,N].  BM=BN=64, BK=16, 256 threads, 4x4 microtile.
template<int BM, int BN, int BK>
__global__ __launch_bounds__(256)
void sgemm(const float* __restrict__ A, const float* __restrict__ B,
           float* __restrict__ C, int M, int N, int K) {
  __shared__ float As[BK][BM + 4];
  __shared__ float Bs[BK][BN];
  const int tid  = threadIdx.x;
  const int brow = blockIdx.y * BM;
  const int bcol = blockIdx.x * BN;
  const int tcol = (tid & 15) * 4;   // 0..60
  const int trow = (tid >> 4) * 4;   // 0..60
  const int am = tid >> 2;           // 0..63 : A row within tile
  const int ak = (tid & 3) * 4;      // 0,4,8,12
  const int bk = tid >> 4;           // 0..15 : B row within tile
  const int bc = (tid & 15) * 4;
  const int arow = brow + am;
  float acc[4][4] = {};
  for (int k0 = 0; k0 < K; k0 += BK) {
    float4 av = make_float4(0.f, 0.f, 0.f, 0.f);
    if (arow < M) av = *(const float4*)&A[(size_t)arow * K + k0 + ak];
    const float4 bv = *(const float4*)&B[(size_t)(k0 + bk) * N + bcol + bc];
    __syncthreads();
    As[ak + 0][am] = av.x; As[ak + 1][am] = av.y;
    As[ak + 2][am] = av.z; As[ak + 3][am] = av.w;
    *(float4*)&Bs[bk][bc] = bv;
    __syncthreads();
#pragma unroll
    for (int kk = 0; kk < BK; ++kk) {
      float ar[4], br[4];
#pragma unroll
      for (int i = 0; i < 4; ++i) ar[i] = As[kk][trow + i];
#pragma unroll
      for (int j = 0; j < 4; ++j) br[j] = Bs[kk][tcol + j];
#pragma unroll
      for (int i = 0; i < 4; ++i)
#pragma unroll
        for (int j = 0; j < 4; ++j)
          acc[i][j] = fmaf(ar[i], br[j], acc[i][j]);
    }
  }
#pragma unroll
  for (int i = 0; i < 4; ++i) {
    const int row = brow + trow + i;
    if (row < M)
      *(float4*)&C[(size_t)row * N + bcol + tcol] =
          make_float4(acc[i][0], acc[i][1], acc[i][2], acc[i][3]);
  }
}

// ------------------------------------------------------------- CSR building
__global__ __launch_bounds__(256)
void zero_ints(int* __restrict__ p, int n) {
  const int i = blockIdx.x * 256 + threadIdx.x;
  if (i < n) p[i] = 0;
}

__global__ __launch_bounds__(256)
void csr_count(const int* __restrict__ ei, int E, int Etot,
               int* __restrict__ count) {
  const int i = blockIdx.x * 256 + threadIdx.x;
  if (i >= Etot) return;
  const int d = (i < E) ? ei[E + i] : (i - E);
  atomicAdd(&count[d], 1);
}

// single-block exclusive scan: count[N] -> rowptr[N+1], cursor[N]
__global__ __launch_bounds__(1024)
void csr_scan(const int* __restrict__ count, int* __restrict__ rowptr,
              int* __restrict__ cursor, int Nn) {
  __shared__ int partial[1024];
  const int t = threadIdx.x;
  const int chunk = (Nn + 1023) / 1024;
  const int b = t * chunk;
  const int e = min(b + chunk, Nn);
  int s = 0;
  for (int i = b; i < e; ++i) s += count[i];
  partial[t] = s;
  __syncthreads();
  for (int off = 1; off < 1024; off <<= 1) {
    const int add = (t >= off) ? partial[t - off] : 0;
    __syncthreads();
    partial[t] += add;
    __syncthreads();
  }
  int run = partial[t] - s;   // exclusive prefix at b
  for (int i = b; i < e; ++i) {
    rowptr[i] = run;
    cursor[i] = run;
    run += count[i];
  }
  if (t == 0) rowptr[Nn] = partial[1023];
}

__global__ __launch_bounds__(256)
void csr_scatter(const int* __restrict__ ei, int E, int Etot,
                 int* __restrict__ cursor, int* __restrict__ srcs) {
  const int i = blockIdx.x * 256 + threadIdx.x;
  if (i >= Etot) return;
  const int s = (i < E) ? ei[i]     : (i - E);
  const int d = (i < E) ? ei[E + i] : (i - E);
  const int pos = atomicAdd(&cursor[d], 1);
  srcs[pos] = s;
}

// ------------------------------------------------- per-node attention logits
template<int H, int C>
__global__ __launch_bounds__(H * C / 4)
void node_att(const float* __restrict__ h, const float* __restrict__ a_src,
              const float* __restrict__ a_dst, float* __restrict__ es,
              float* __restrict__ ed) {
  const int n = blockIdx.x;
  const int t = threadIdx.x;
  const int c4 = t * 4;
  const int head = c4 / C;
  const float4 v  = *(const float4*)&h[(size_t)n * (H * C) + c4];
  const float4 as = *(const float4*)&a_src[c4];
  const float4 ad = *(const float4*)&a_dst[c4];
  float ps = v.x * as.x + v.y * as.y + v.z * as.z + v.w * as.w;
  float pd = v.x * ad.x + v.y * ad.y + v.z * ad.z + v.w * ad.w;
#pragma unroll
  for (int off = C / 8; off >= 1; off >>= 1) {
    ps += __shfl_xor(ps, off);
    pd += __shfl_xor(pd, off);
  }
  if ((t & (C / 4 - 1)) == 0) {
    es[n * H + head] = ps;
    ed[n * H + head] = pd;
  }
}

// ---------------------------------------------- gather-based GAT aggregation
// one wave per node (4 waves / block). Softmax denom in-wave, then gather+FMA.
// F = H*C/64 floats per lane.
template<int H, int C>
__global__ __launch_bounds__(256)
void gat_agg(const int* __restrict__ rowptr, const int* __restrict__ srcs,
             const float* __restrict__ h, const float* __restrict__ es,
             const float* __restrict__ ed, float* __restrict__ out, int Nn) {
  constexpr int HC = H * C;
  constexpr int F  = HC / 64;          // 8 (layer1) or 4 (layer2)
  const int wave = threadIdx.x >> 6;
  const int lane = threadIdx.x & 63;
  const int n = blockIdx.x * 4 + wave;
  if (n >= Nn) return;
  const int beg = rowptr[n];
  const int deg = rowptr[n + 1] - beg;

  // ---- pass 1: per-head softmax denominator ----
  const int myh = lane & (H - 1);                    // head for strided items
  const float edv = ed[n * H + myh];
  float ssum = 0.f;
  for (int it = lane; it < deg * H; it += 64) {
    const int j = (H == 4) ? (it >> 2) : it;
    const int src = srcs[beg + j];
    float e = es[src * H + myh] + edv;
    e = (e > 0.f) ? e : LRELU_SLOPE * e;
    ssum += __expf(e);
  }
#pragma unroll
  for (int off = H; off < 64; off <<= 1) ssum += __shfl_xor(ssum, off);

  const int hl = (lane * F) / C;                     // head of my channel slice
  const float s_mine = __shfl(ssum, hl) + 1e-16f;
  const float edh = ed[n * H + hl];

  // ---- pass 2: gather + weighted accumulate ----
  float acc[F];
#pragma unroll
  for (int i = 0; i < F; ++i) acc[i] = 0.f;
  for (int j = 0; j < deg; ++j) {
    const int src = srcs[beg + j];
    float e = es[src * H + hl] + edh;
    e = (e > 0.f) ? e : LRELU_SLOPE * e;
    const float alpha = __expf(e) / s_mine;
    const float* hp = &h[(size_t)src * HC + lane * F];
    const float4 v0 = *(const float4*)hp;
    acc[0] = fmaf(v0.x, alpha, acc[0]);
    acc[1] = fmaf(v0.y, alpha, acc[1]);
    acc[2] = fmaf(v0.z, alpha, acc[2]);
    acc[3] = fmaf(v0.w, alpha, acc[3]);
    if constexpr (F == 8) {
      const float4 v1 = *(const float4*)(hp + 4);
      acc[4] = fmaf(v1.x, alpha, acc[4]);
      acc[5] = fmaf(v1.y, alpha, acc[5]);
      acc[6] = fmaf(v1.z, alpha, acc[6]);
      acc[7] = fmaf(v1.w, alpha, acc[7]);
    }
  }
  float* op = &out[(size_t)n * HC + lane * F];
  *(float4*)op = make_float4(acc[0], acc[1], acc[2], acc[3]);
  if constexpr (F == 8)
    *(float4*)(op + 4) = make_float4(acc[4], acc[5], acc[6], acc[7]);
}

// -------------------------------------------------------- LayerNorm (+ReLU)
template<int D, bool RELU>
__global__ __launch_bounds__(D / 4)
void ln_kernel(float* __restrict__ x, const float* __restrict__ bias,
               const float* __restrict__ g, const float* __restrict__ b) {
  const int n = blockIdx.x;
  const int t = threadIdx.x;
  float4 v = *(float4*)&x[(size_t)n * D + t * 4];
  const float4 bb = *(const float4*)&bias[t * 4];
  v.x += bb.x; v.y += bb.y; v.z += bb.z; v.w += bb.w;
  float sum = v.x + v.y + v.z + v.w;
  float sq  = v.x * v.x + v.y * v.y + v.z * v.z + v.w * v.w;
#pragma unroll
  for (int off = 32; off >= 1; off >>= 1) {
    sum += __shfl_xor(sum, off);
    sq  += __shfl_xor(sq, off);
  }
  float tsum, tsq;
  if constexpr (D / 4 > 64) {
    __shared__ float red[2][2];
    const int wid = t >> 6;
    if ((t & 63) == 0) { red[wid][0] = sum; red[wid][1] = sq; }
    __syncthreads();
    tsum = red[0][0] + red[1][0];
    tsq  = red[0][1] + red[1][1];
  } else {
    tsum = sum; tsq = sq;
  }
  const float mu  = tsum / D;
  const float var = tsq / D - mu * mu;
  const float r   = rsqrtf(var + 1e-5f);
  const float4 gg  = *(const float4*)&g[t * 4];
  const float4 bl  = *(const float4*)&b[t * 4];
  float4 y;
  y.x = (v.x - mu) * r * gg.x + bl.x;
  y.y = (v.y - mu) * r * gg.y + bl.y;
  y.z = (v.z - mu) * r * gg.z + bl.z;
  y.w = (v.w - mu) * r * gg.w + bl.w;
  if constexpr (RELU) {
    y.x = fmaxf(y.x, 0.f); y.y = fmaxf(y.y, 0.f);
    y.z = fmaxf(y.z, 0.f); y.w = fmaxf(y.w, 0.f);
  }
  *(float4*)&x[(size_t)n * D + t * 4] = y;
}

// ---------------------------------------------------------- global mean pool
__global__ __launch_bounds__(256)
void pool_kernel(const float* __restrict__ x, const int* __restrict__ batch,
                 float* __restrict__ out, int n_nodes) {
  const int g = blockIdx.x;
  const int t = threadIdx.x;
  int lo = 0, hi = n_nodes;
  while (lo < hi) { int mid = (lo + hi) >> 1; if (batch[mid] < g) lo = mid + 1; else hi = mid; }
  const int start = lo;
  hi = n_nodes;
  while (lo < hi) { int mid = (lo + hi) >> 1; if (batch[mid] < g + 1) lo = mid + 1; else hi = mid; }
  const int end = lo;
  float sum = 0.f;
  for (int r = start; r < end; ++r) sum += x[(size_t)r * 256 + t];
  out[g * 256 + t] = sum / fmaxf((float)(end - start), 1.f);
}

// ---------------------------------------------------------------------------
extern "C" void kernel_launch(void* const* d_in, const int* in_sizes, int n_in,
                              void* d_out, int out_size, void* d_ws, size_t ws_size,
                              hipStream_t stream) {
  const float* x    = (const float*)d_in[0];
  const int*   ei   = (const int*)d_in[1];
  const int*   batch= (const int*)d_in[2];
  const float* W1   = (const float*)d_in[3];
  const float* as1  = (const float*)d_in[4];
  const float* ad1  = (const float*)d_in[5];
  const float* b1   = (const float*)d_in[6];
  const float* g1   = (const float*)d_in[7];
  const float* be1  = (const float*)d_in[8];
  const float* W2   = (const float*)d_in[9];
  const float* as2  = (const float*)d_in[10];
  const float* ad2  = (const float*)d_in[11];
  const float* b2   = (const float*)d_in[12];
  const float* g2   = (const float*)d_in[13];
  const float* be2  = (const float*)d_in[14];

  const int N    = in_sizes[0] / 256;   // 50000
  const int E    = in_sizes[1] / 2;     // 400000
  const int Etot = E + N;               // self-loops appended

  float* ws   = (float*)d_ws;
  float* h1   = ws;                            // N*512 f32
  float* out1 = h1   + (size_t)N * 512;        // N*512 f32
  float* es   = out1 + (size_t)N * 512;        // N*4
  float* ed   = es   + (size_t)N * 4;          // N*4
  int*   count  = (int*)(ed + (size_t)N * 4);  // N
  int*   rowptr = count  + N;                  // N+1
  int*   cursor = rowptr + N + 1;              // N
  int*   srcs   = cursor + N;                  // Etot
  // layer-2 buffers alias layer-1 regions dead by then
  float* h2   = h1;                            // N*256
  float* out2 = h1 + (size_t)N * 256;          // N*256

  const int eb = (Etot + 255) / 256;

  // ---- CSR build (edges grouped by dst) ----
  zero_ints<<<(N + 255) / 256, 256, 0, stream>>>(count, N);
  csr_count<<<eb, 256, 0, stream>>>(ei, E, Etot, count);
  csr_scan<<<1, 1024, 0, stream>>>(count, rowptr, cursor, N);
  csr_scatter<<<eb, 256, 0, stream>>>(ei, E, Etot, cursor, srcs);

  // ---- layer 1: GATConv(256 -> 4x128) ----
  sgemm<64, 64, 16><<<dim3(512 / 64, (N + 63) / 64), 256, 0, stream>>>(
      x, W1, h1, N, 512, 256);
  node_att<4, 128><<<N, 128, 0, stream>>>(h1, as1, ad1, es, ed);
  gat_agg<4, 128><<<(N + 3) / 4, 256, 0, stream>>>(rowptr, srcs, h1, es, ed, out1, N);
  ln_kernel<512, true><<<N, 128, 0, stream>>>(out1, b1, g1, be1);

  // ---- layer 2: GATConv(512 -> 1x256) ----
  sgemm<64, 64, 16><<<dim3(256 / 64, (N + 63) / 64), 256, 0, stream>>>(
      out1, W2, h2, N, 256, 512);
  node_att<1, 256><<<N, 64, 0, stream>>>(h2, as2, ad2, es, ed);
  gat_agg<1, 256><<<(N + 3) / 4, 256, 0, stream>>>(rowptr, srcs, h2, es, ed, out2, N);
  ln_kernel<256, false><<<N, 64, 0, stream>>>(out2, b2, g2, be2);

  // ---- global mean pool ----
  pool_kernel<<<GN, 256, 0, stream>>>(out2, batch, (float*)d_out, N);
}

// Round 3
// 486.929 us; speedup vs baseline: 10.4936x; 2.0509x over previous
//
#include <hip/hip_runtime.h>
#include <hip/hip_bf16.h>
#include <cstdint>

#define LRELU_SLOPE 0.2f

typedef short bf16x8 __attribute__((ext_vector_type(8)));
typedef float f32x4  __attribute__((ext_vector_type(4)));

__device__ __forceinline__ float b2f(unsigned short u) {
  return __uint_as_float(((unsigned int)u) << 16);
}
__device__ __forceinline__ unsigned short f2b(float f) {  // RNE
  unsigned int u = __float_as_uint(f);
  return (unsigned short)((u + 0x7fff + ((u >> 16) & 1)) >> 16);
}

__device__ __forceinline__ void gload16(const void* g, void* l) {
  __builtin_amdgcn_global_load_lds(
      (const __attribute__((address_space(1))) unsigned int*)g,
      (__attribute__((address_space(3))) unsigned int*)l, 16, 0, 0);
}

// ------------------------------------------------------------------- utility
__global__ __launch_bounds__(256)
void zero_ints(int* __restrict__ p, int n) {
  const int i = blockIdx.x * 256 + threadIdx.x;
  if (i < n) p[i] = 0;
}

// f32 -> bf16 convert with zero-padded tail rows. one thread = 4 elems.
__global__ __launch_bounds__(256)
void cvt_bf16_pad(const float* __restrict__ x, unsigned short* __restrict__ o,
                  int M, int D, int Mpad) {
  const int i = blockIdx.x * 256 + threadIdx.x;
  const int per_row = D / 4;
  if (i >= Mpad * per_row) return;
  const int row = i / per_row;
  const int c4  = (i % per_row) * 4;
  ushort4 v = make_ushort4(0, 0, 0, 0);
  if (row < M) {
    const float4 f = *(const float4*)&x[(size_t)row * D + c4];
    v = make_ushort4(f2b(f.x), f2b(f.y), f2b(f.z), f2b(f.w));
  }
  *(ushort4*)&o[(size_t)row * D + c4] = v;
}

// W[K][N] f32 -> WT[N][K] bf16
__global__ __launch_bounds__(256)
void cvt_wt(const float* __restrict__ W, unsigned short* __restrict__ WT,
            int K, int N) {
  const int j = blockIdx.x * 256 + threadIdx.x;
  if (j >= N * K) return;
  const int n = j / K, k = j % K;
  WT[j] = f2b(W[(size_t)k * N + n]);
}

// ------------------------------------------------------------- CSR building
__global__ __launch_bounds__(256)
void csr_count(const int* __restrict__ ei, int E, int Etot,
               int* __restrict__ count) {
  const int i = blockIdx.x * 256 + threadIdx.x;
  if (i >= Etot) return;
  const int d = (i < E) ? ei[E + i] : (i - E);
  atomicAdd(&count[d], 1);
}

__global__ __launch_bounds__(1024)
void csr_scan(const int* __restrict__ count, int* __restrict__ rowptr,
              int* __restrict__ cursor, int Nn) {
  __shared__ int partial[1024];
  const int t = threadIdx.x;
  const int chunk = (Nn + 1023) / 1024;
  const int b = t * chunk;
  const int e = min(b + chunk, Nn);
  int s = 0;
  for (int i = b; i < e; ++i) s += count[i];
  partial[t] = s;
  __syncthreads();
  for (int off = 1; off < 1024; off <<= 1) {
    const int add = (t >= off) ? partial[t - off] : 0;
    __syncthreads();
    partial[t] += add;
    __syncthreads();
  }
  int run = partial[t] - s;
  for (int i = b; i < e; ++i) {
    rowptr[i] = run;
    cursor[i] = run;
    run += count[i];
  }
  if (t == 0) rowptr[Nn] = partial[1023];
}

__global__ __launch_bounds__(256)
void csr_scatter(const int* __restrict__ ei, int E, int Etot,
                 int* __restrict__ cursor, int* __restrict__ srcs) {
  const int i = blockIdx.x * 256 + threadIdx.x;
  if (i >= Etot) return;
  const int s = (i < E) ? ei[i]     : (i - E);
  const int d = (i < E) ? ei[E + i] : (i - E);
  const int pos = atomicAdd(&cursor[d], 1);
  srcs[pos] = s;
}

// ------------------------------------------------------- bf16 MFMA GEMM
// C[M,N](bf16) = A[Mpad,K](bf16) @ BT[N,K](bf16)^T.  128x128 tile, BK=32,
// 256 thr (4 waves, 2x2 of 64x64), global_load_lds staging, XOR slot swizzle.
template<int KSTEPS>
__global__ __launch_bounds__(256)
void gemm_bf16(const unsigned short* __restrict__ A,
               const unsigned short* __restrict__ BT,
               unsigned short* __restrict__ C, int M, int Nn, int K) {
  __shared__ unsigned short As[128 * 32];
  __shared__ unsigned short Bs[128 * 32];
  const int tid  = threadIdx.x;
  const int lane = tid & 63;
  const int wave = tid >> 6;
  const int wm = wave >> 1, wn = wave & 1;
  const int brow = blockIdx.y * 128;
  const int bcol = blockIdx.x * 128;
  // staging: thread t -> LDS bytes [t*16, t*16+16) (+4096 for round 2)
  const int srow  = tid >> 2;            // 0..63
  const int sslot = tid & 3;
  const int sswz  = sslot ^ (srow & 3);  // (srow+64)&3 == srow&3
  const size_t aBase0 = (size_t)(brow + srow) * K + sswz * 8;
  const size_t aBase1 = (size_t)(brow + 64 + srow) * K + sswz * 8;
  const size_t bBase0 = (size_t)(bcol + srow) * K + sswz * 8;
  const size_t bBase1 = (size_t)(bcol + 64 + srow) * K + sswz * 8;
  unsigned short* ldsA0 = &As[srow * 32 + sslot * 8];
  unsigned short* ldsA1 = &As[(64 + srow) * 32 + sslot * 8];
  unsigned short* ldsB0 = &Bs[srow * 32 + sslot * 8];
  unsigned short* ldsB1 = &Bs[(64 + srow) * 32 + sslot * 8];

  f32x4 acc[4][4] = {};
  const int u   = lane >> 4;
  const int r15 = lane & 15;
  const int sw  = u ^ (r15 & 3);   // (row&3)==(lane&3) for any 16-aligned base

  for (int ks = 0; ks < KSTEPS; ++ks) {
    const int k0 = ks * 32;
    __syncthreads();
    gload16(A + aBase0 + k0, ldsA0);
    gload16(A + aBase1 + k0, ldsA1);
    gload16(BT + bBase0 + k0, ldsB0);
    gload16(BT + bBase1 + k0, ldsB1);
    asm volatile("s_waitcnt vmcnt(0)" ::: "memory");
    __syncthreads();
    bf16x8 af[4], bfv[4];
#pragma unroll
    for (int m = 0; m < 4; ++m) {
      const int row = wm * 64 + m * 16 + r15;
      af[m]  = *(const bf16x8*)&As[row * 32 + sw * 8];
      const int col = wn * 64 + m * 16 + r15;
      bfv[m] = *(const bf16x8*)&Bs[col * 32 + sw * 8];
    }
#pragma unroll
    for (int m = 0; m < 4; ++m)
#pragma unroll
      for (int n = 0; n < 4; ++n)
        acc[m][n] = __builtin_amdgcn_mfma_f32_16x16x32_bf16(
            af[m], bfv[n], acc[m][n], 0, 0, 0);
  }
  // epilogue: C row = (lane>>4)*4 + reg, col = lane&15  [m89-verified layout]
#pragma unroll
  for (int m = 0; m < 4; ++m) {
    const int r0 = brow + wm * 64 + m * 16 + u * 4;
#pragma unroll
    for (int n = 0; n < 4; ++n) {
      const int cc = bcol + wn * 64 + n * 16 + r15;
#pragma unroll
      for (int r = 0; r < 4; ++r)
        if (r0 + r < M) C[(size_t)(r0 + r) * Nn + cc] = f2b(acc[m][n][r]);
    }
  }
}

// ------------------------------------------------- per-node attention logits
template<int H, int C>
__global__ __launch_bounds__(H * C / 4)
void node_att(const unsigned short* __restrict__ h,
              const float* __restrict__ a_src, const float* __restrict__ a_dst,
              float* __restrict__ es, float* __restrict__ ed) {
  const int n = blockIdx.x;
  const int t = threadIdx.x;
  const int c4 = t * 4;
  const int head = c4 / C;
  const ushort4 hv = *(const ushort4*)&h[(size_t)n * (H * C) + c4];
  const float4 as = *(const float4*)&a_src[c4];
  const float4 ad = *(const float4*)&a_dst[c4];
  const float x0 = b2f(hv.x), x1 = b2f(hv.y), x2 = b2f(hv.z), x3 = b2f(hv.w);
  float ps = x0 * as.x + x1 * as.y + x2 * as.z + x3 * as.w;
  float pd = x0 * ad.x + x1 * ad.y + x2 * ad.z + x3 * ad.w;
#pragma unroll
  for (int off = C / 8; off >= 1; off >>= 1) {
    ps += __shfl_xor(ps, off);
    pd += __shfl_xor(pd, off);
  }
  if ((t & (C / 4 - 1)) == 0) {
    es[n * H + head] = ps;
    ed[n * H + head] = pd;
  }
}

// ---------------------------------------------- gather-based GAT aggregation
template<int H, int C>
__global__ __launch_bounds__(256)
void gat_agg(const int* __restrict__ rowptr, const int* __restrict__ srcs,
             const unsigned short* __restrict__ h, const float* __restrict__ es,
             const float* __restrict__ ed, float* __restrict__ out, int Nn) {
  constexpr int HC = H * C;
  constexpr int F  = HC / 64;          // 8 (layer1) or 4 (layer2)
  const int wave = threadIdx.x >> 6;
  const int lane = threadIdx.x & 63;
  const int n = blockIdx.x * 4 + wave;
  if (n >= Nn) return;
  const int beg = rowptr[n];
  const int deg = rowptr[n + 1] - beg;

  // pass 1: per-head softmax denominator
  const int myh = lane & (H - 1);
  const float edv = ed[n * H + myh];
  float ssum = 0.f;
  for (int it = lane; it < deg * H; it += 64) {
    const int j = (H == 4) ? (it >> 2) : it;
    const int src = srcs[beg + j];
    float e = es[src * H + myh] + edv;
    e = (e > 0.f) ? e : LRELU_SLOPE * e;
    ssum += __expf(e);
  }
#pragma unroll
  for (int off = H; off < 64; off <<= 1) ssum += __shfl_xor(ssum, off);

  const int hl = (lane * F) / C;
  const float s_mine = __shfl(ssum, hl) + 1e-16f;
  const float edh = ed[n * H + hl];

  // pass 2: gather + weighted accumulate
  float acc[F];
#pragma unroll
  for (int i = 0; i < F; ++i) acc[i] = 0.f;
  for (int j = 0; j < deg; ++j) {
    const int src = srcs[beg + j];
    float e = es[src * H + hl] + edh;
    e = (e > 0.f) ? e : LRELU_SLOPE * e;
    const float alpha = __expf(e) / s_mine;
    const unsigned short* hp = &h[(size_t)src * HC + lane * F];
    if constexpr (F == 8) {
      const ushort4 v0 = *(const ushort4*)hp;
      const ushort4 v1 = *(const ushort4*)(hp + 4);
      acc[0] = fmaf(b2f(v0.x), alpha, acc[0]);
      acc[1] = fmaf(b2f(v0.y), alpha, acc[1]);
      acc[2] = fmaf(b2f(v0.z), alpha, acc[2]);
      acc[3] = fmaf(b2f(v0.w), alpha, acc[3]);
      acc[4] = fmaf(b2f(v1.x), alpha, acc[4]);
      acc[5] = fmaf(b2f(v1.y), alpha, acc[5]);
      acc[6] = fmaf(b2f(v1.z), alpha, acc[6]);
      acc[7] = fmaf(b2f(v1.w), alpha, acc[7]);
    } else {
      const ushort4 v0 = *(const ushort4*)hp;
      acc[0] = fmaf(b2f(v0.x), alpha, acc[0]);
      acc[1] = fmaf(b2f(v0.y), alpha, acc[1]);
      acc[2] = fmaf(b2f(v0.z), alpha, acc[2]);
      acc[3] = fmaf(b2f(v0.w), alpha, acc[3]);
    }
  }
  float* op = &out[(size_t)n * HC + lane * F];
  *(float4*)op = make_float4(acc[0], acc[1], acc[2], acc[3]);
  if constexpr (F == 8)
    *(float4*)(op + 4) = make_float4(acc[4], acc[5], acc[6], acc[7]);
}

// -------------------------------------------------------- LayerNorm (+ReLU)
// BFOUT: write bf16 to `o` (GEMM input); else f32 in place to x.
template<int D, bool RELU, bool BFOUT>
__global__ __launch_bounds__(D / 4)
void ln_kernel(float* __restrict__ x, unsigned short* __restrict__ o,
               const float* __restrict__ bias, const float* __restrict__ g,
               const float* __restrict__ b) {
  const int n = blockIdx.x;
  const int t = threadIdx.x;
  float4 v = *(float4*)&x[(size_t)n * D + t * 4];
  const float4 bb = *(const float4*)&bias[t * 4];
  v.x += bb.x; v.y += bb.y; v.z += bb.z; v.w += bb.w;
  float sum = v.x + v.y + v.z + v.w;
  float sq  = v.x * v.x + v.y * v.y + v.z * v.z + v.w * v.w;
#pragma unroll
  for (int off = 32; off >= 1; off >>= 1) {
    sum += __shfl_xor(sum, off);
    sq  += __shfl_xor(sq, off);
  }
  float tsum, tsq;
  if constexpr (D / 4 > 64) {
    __shared__ float red[2][2];
    const int wid = t >> 6;
    if ((t & 63) == 0) { red[wid][0] = sum; red[wid][1] = sq; }
    __syncthreads();
    tsum = red[0][0] + red[1][0];
    tsq  = red[0][1] + red[1][1];
  } else {
    tsum = sum; tsq = sq;
  }
  const float mu  = tsum / D;
  const float var = tsq / D - mu * mu;
  const float r   = rsqrtf(var + 1e-5f);
  const float4 gg = *(const float4*)&g[t * 4];
  const float4 bl = *(const float4*)&b[t * 4];
  float4 y;
  y.x = (v.x - mu) * r * gg.x + bl.x;
  y.y = (v.y - mu) * r * gg.y + bl.y;
  y.z = (v.z - mu) * r * gg.z + bl.z;
  y.w = (v.w - mu) * r * gg.w + bl.w;
  if constexpr (RELU) {
    y.x = fmaxf(y.x, 0.f); y.y = fmaxf(y.y, 0.f);
    y.z = fmaxf(y.z, 0.f); y.w = fmaxf(y.w, 0.f);
  }
  if constexpr (BFOUT) {
    *(ushort4*)&o[(size_t)n * D + t * 4] =
        make_ushort4(f2b(y.x), f2b(y.y), f2b(y.z), f2b(y.w));
  } else {
    *(float4*)&x[(size_t)n * D + t * 4] = y;
  }
}

// ---------------------------------------------------------- global mean pool
__global__ __launch_bounds__(256)
void pool_partial(const float* __restrict__ x, const int* __restrict__ batch,
                  float* __restrict__ tmp, int* __restrict__ cnt, int Nn) {
  const int r0 = blockIdx.x * 64;
  const int rend = min(r0 + 64, Nn);
  const int t = threadIdx.x;
  float acc = 0.f;
  int cur = batch[r0];
  int seglen = 0;
  for (int r = r0; r < rend; ++r) {
    const int g = batch[r];
    if (g != cur) {
      unsafeAtomicAdd(&tmp[cur * 256 + t], acc);
      if (t == 0) atomicAdd(&cnt[cur], seglen);
      acc = 0.f; seglen = 0; cur = g;
    }
    acc += x[(size_t)r * 256 + t];
    ++seglen;
  }
  unsafeAtomicAdd(&tmp[cur * 256 + t], acc);
  if (t == 0) atomicAdd(&cnt[cur], seglen);
}

__global__ __launch_bounds__(256)
void pool_final(const float* __restrict__ tmp, const int* __restrict__ cnt,
                float* __restrict__ out) {
  const int g = blockIdx.x;
  const int t = threadIdx.x;
  out[g * 256 + t] = tmp[g * 256 + t] / fmaxf((float)cnt[g], 1.f);
}

// ---------------------------------------------------------------------------
extern "C" void kernel_launch(void* const* d_in, const int* in_sizes, int n_in,
                              void* d_out, int out_size, void* d_ws, size_t ws_size,
                              hipStream_t stream) {
  const float* x    = (const float*)d_in[0];
  const int*   ei   = (const int*)d_in[1];
  const int*   batch= (const int*)d_in[2];
  const float* W1   = (const float*)d_in[3];
  const float* as1  = (const float*)d_in[4];
  const float* ad1  = (const float*)d_in[5];
  const float* b1   = (const float*)d_in[6];
  const float* g1   = (const float*)d_in[7];
  const float* be1  = (const float*)d_in[8];
  const float* W2   = (const float*)d_in[9];
  const float* as2  = (const float*)d_in[10];
  const float* ad2  = (const float*)d_in[11];
  const float* b2   = (const float*)d_in[12];
  const float* g2   = (const float*)d_in[13];
  const float* be2  = (const float*)d_in[14];

  const int N    = in_sizes[0] / 256;   // 50000
  const int E    = in_sizes[1] / 2;     // 400000
  const int Etot = E + N;
  const int Mpad = ((N + 127) / 128) * 128;   // 50048

  // ---------------- workspace layout (f32 units) ----------------
  float* ws = (float*)d_ws;
  float* out1 = ws;                                   // N*512 f32 (also out2)
  unsigned short* A2bf = (unsigned short*)(out1 + (size_t)N * 512); // Mpad*512 bf16
  unsigned short* A1bf = A2bf;                        // Mpad*256 bf16 (aliases A2bf head; dead before ln1 writes)
  unsigned short* h1bf = A2bf + (size_t)Mpad * 512;   // N*512 bf16 (also h2bf N*256)
  unsigned short* W1T  = h1bf + (size_t)N * 512;      // 512*256 bf16
  unsigned short* W2T  = W1T + 512 * 256;             // 256*512 bf16
  float* es   = (float*)(W2T + 512 * 256);            // N*4
  float* ed   = es + (size_t)N * 4;                   // N*4
  int* count  = (int*)(ed + (size_t)N * 4);           // N
  int* rowptr = count + N;                            // N+1
  int* cursor = rowptr + N + 1;                       // N
  int* srcs   = cursor + N;                           // Etot
  float* ptmp = (float*)(srcs + Etot);                // 64*256
  int*   pcnt = (int*)(ptmp + 64 * 256);              // 64
  float* out2 = out1;
  unsigned short* h2bf = h1bf;

  const int eb = (Etot + 255) / 256;

  // ---- zero-init (count, A2 pad rows, pool accumulators) ----
  zero_ints<<<(N + 255) / 256, 256, 0, stream>>>(count, N);
  zero_ints<<<((Mpad - N) * 512 / 2 + 255) / 256, 256, 0, stream>>>(
      (int*)(A2bf + (size_t)N * 512), (Mpad - N) * 512 / 2);
  zero_ints<<<(64 * 256 + 64 + 255) / 256, 256, 0, stream>>>((int*)ptmp, 64 * 256 + 64);

  // ---- CSR build ----
  csr_count<<<eb, 256, 0, stream>>>(ei, E, Etot, count);
  csr_scan<<<1, 1024, 0, stream>>>(count, rowptr, cursor, N);
  csr_scatter<<<eb, 256, 0, stream>>>(ei, E, Etot, cursor, srcs);

  // ---- operand conversion ----
  cvt_bf16_pad<<<((size_t)Mpad * 64 + 255) / 256, 256, 0, stream>>>(x, A1bf, N, 256, Mpad);
  cvt_wt<<<(512 * 256 + 255) / 256, 256, 0, stream>>>(W1, W1T, 256, 512);
  cvt_wt<<<(512 * 256 + 255) / 256, 256, 0, stream>>>(W2, W2T, 512, 256);

  // ---- layer 1: GATConv(256 -> 4x128) ----
  gemm_bf16<8><<<dim3(4, Mpad / 128), 256, 0, stream>>>(A1bf, W1T, h1bf, N, 512, 256);
  node_att<4, 128><<<N, 128, 0, stream>>>(h1bf, as1, ad1, es, ed);
  gat_agg<4, 128><<<(N + 3) / 4, 256, 0, stream>>>(rowptr, srcs, h1bf, es, ed, out1, N);
  ln_kernel<512, true, true><<<N, 128, 0, stream>>>(out1, A2bf, b1, g1, be1);

  // ---- layer 2: GATConv(512 -> 1x256) ----
  gemm_bf16<16><<<dim3(2, Mpad / 128), 256, 0, stream>>>(A2bf, W2T, h2bf, N, 256, 512);
  node_att<1, 256><<<N, 64, 0, stream>>>(h2bf, as2, ad2, es, ed);
  gat_agg<1, 256><<<(N + 3) / 4, 256, 0, stream>>>(rowptr, srcs, h2bf, es, ed, out2, N);
  ln_kernel<256, false, false><<<N, 64, 0, stream>>>(out2, nullptr, b2, g2, be2);

  // ---- global mean pool ----
  pool_partial<<<(N + 63) / 64, 256, 0, stream>>>(out2, batch, ptmp, pcnt, N);
  pool_final<<<64, 256, 0, stream>>>(ptmp, pcnt, (float*)d_out);
}

// Round 4
// 322.810 us; speedup vs baseline: 15.8286x; 1.5084x over previous
//
#include <hip/hip_runtime.h>
#include <hip/hip_bf16.h>
#include <cstdint>

#define LRELU_SLOPE 0.2f

typedef short bf16x8 __attribute__((ext_vector_type(8)));
typedef float f32x4  __attribute__((ext_vector_type(4)));

__device__ __forceinline__ float b2f(unsigned short u) {
  return __uint_as_float(((unsigned int)u) << 16);
}
__device__ __forceinline__ unsigned short f2b(float f) {  // RNE
  unsigned int u = __float_as_uint(f);
  return (unsigned short)((u + 0x7fff + ((u >> 16) & 1)) >> 16);
}

__device__ __forceinline__ void gload16(const void* g, void* l) {
  __builtin_amdgcn_global_load_lds(
      (const __attribute__((address_space(1))) unsigned int*)g,
      (__attribute__((address_space(3))) unsigned int*)l, 16, 0, 0);
}

// ------------------------------------------------------------------- convert
__global__ __launch_bounds__(256)
void cvt_bf16_pad(const float* __restrict__ x, unsigned short* __restrict__ o,
                  int M, int D, int Mpad) {
  const int i = blockIdx.x * 256 + threadIdx.x;
  const int per_row = D / 4;
  if (i >= Mpad * per_row) return;
  const int row = i / per_row;
  const int c4  = (i % per_row) * 4;
  ushort4 v = make_ushort4(0, 0, 0, 0);
  if (row < M) {
    const float4 f = *(const float4*)&x[(size_t)row * D + c4];
    v = make_ushort4(f2b(f.x), f2b(f.y), f2b(f.z), f2b(f.w));
  }
  *(ushort4*)&o[(size_t)row * D + c4] = v;
}

__global__ __launch_bounds__(256)
void cvt_wt(const float* __restrict__ W, unsigned short* __restrict__ WT,
            int K, int N) {
  const int j = blockIdx.x * 256 + threadIdx.x;
  if (j >= N * K) return;
  const int n = j / K, k = j % K;
  WT[j] = f2b(W[(size_t)k * N + n]);
}

// ------------------------------------------------------------- CSR building
__global__ __launch_bounds__(256)
void csr_count(const int* __restrict__ ei, int E, int Etot,
               int* __restrict__ count) {
  const int i = blockIdx.x * 256 + threadIdx.x;
  if (i >= Etot) return;
  const int d = (i < E) ? ei[E + i] : (i - E);
  atomicAdd(&count[d], 1);
}

// --- parallel exclusive scan over count[N]: 1024 elems / block ---
__global__ __launch_bounds__(256)
void scan_blocksum(const int* __restrict__ count, int* __restrict__ bsum, int Nn) {
  const int i0 = blockIdx.x * 1024 + threadIdx.x * 4;
  int s = 0;
#pragma unroll
  for (int k = 0; k < 4; ++k) { const int i = i0 + k; if (i < Nn) s += count[i]; }
#pragma unroll
  for (int off = 1; off < 64; off <<= 1) s += __shfl_xor(s, off);
  __shared__ int ws[4];
  if ((threadIdx.x & 63) == 0) ws[threadIdx.x >> 6] = s;
  __syncthreads();
  if (threadIdx.x == 0) bsum[blockIdx.x] = ws[0] + ws[1] + ws[2] + ws[3];
}

__global__ __launch_bounds__(64)
void scan_top(const int* __restrict__ bsum, int* __restrict__ boff,
              int* __restrict__ rowptrN, int nb) {
  const int t = threadIdx.x;
  const int v = (t < nb) ? bsum[t] : 0;
  int incl = v;
#pragma unroll
  for (int off = 1; off < 64; off <<= 1) {
    const int u = __shfl_up(incl, off);
    if (t >= off) incl += u;
  }
  if (t < nb) boff[t] = incl - v;
  if (t == 63) *rowptrN = incl;
}

__global__ __launch_bounds__(256)
void scan_apply(const int* __restrict__ count, const int* __restrict__ boff,
                int* __restrict__ rowptr, int* __restrict__ cursor, int Nn) {
  const int t = threadIdx.x;
  const int lane = t & 63;
  const int w = t >> 6;
  const int i0 = blockIdx.x * 1024 + t * 4;
  int c[4]; int s = 0;
#pragma unroll
  for (int k = 0; k < 4; ++k) { const int i = i0 + k; c[k] = (i < Nn) ? count[i] : 0; s += c[k]; }
  int incl = s;
#pragma unroll
  for (int off = 1; off < 64; off <<= 1) {
    const int u = __shfl_up(incl, off);
    if (lane >= off) incl += u;
  }
  __shared__ int ws[4];
  if (lane == 63) ws[w] = incl;
  __syncthreads();
  int woff = 0;
  for (int k = 0; k < w; ++k) woff += ws[k];
  int base = boff[blockIdx.x] + woff + incl - s;
#pragma unroll
  for (int k = 0; k < 4; ++k) {
    const int i = i0 + k;
    if (i < Nn) { rowptr[i] = base; cursor[i] = base; base += c[k]; }
  }
}

__global__ __launch_bounds__(256)
void csr_scatter(const int* __restrict__ ei, int E, int Etot,
                 int* __restrict__ cursor, int* __restrict__ srcs) {
  const int i = blockIdx.x * 256 + threadIdx.x;
  if (i >= Etot) return;
  const int s = (i < E) ? ei[i]     : (i - E);
  const int d = (i < E) ? ei[E + i] : (i - E);
  const int pos = atomicAdd(&cursor[d], 1);
  srcs[pos] = s;
}

// ------------------------------------------------------- bf16 MFMA GEMM
// C[M,N](bf16) = A[Mpad,K](bf16) @ BT[N,K](bf16)^T.  128x128 tile, BK=32.
template<int KSTEPS>
__global__ __launch_bounds__(256)
void gemm_bf16(const unsigned short* __restrict__ A,
               const unsigned short* __restrict__ BT,
               unsigned short* __restrict__ C, int M, int Nn, int K) {
  __shared__ unsigned short As[128 * 32];
  __shared__ unsigned short Bs[128 * 32];
  const int tid  = threadIdx.x;
  const int lane = tid & 63;
  const int wave = tid >> 6;
  const int wm = wave >> 1, wn = wave & 1;
  const int brow = blockIdx.y * 128;
  const int bcol = blockIdx.x * 128;
  const int srow  = tid >> 2;
  const int sslot = tid & 3;
  const int sswz  = sslot ^ (srow & 3);
  const size_t aBase0 = (size_t)(brow + srow) * K + sswz * 8;
  const size_t aBase1 = (size_t)(brow + 64 + srow) * K + sswz * 8;
  const size_t bBase0 = (size_t)(bcol + srow) * K + sswz * 8;
  const size_t bBase1 = (size_t)(bcol + 64 + srow) * K + sswz * 8;
  unsigned short* ldsA0 = &As[srow * 32 + sslot * 8];
  unsigned short* ldsA1 = &As[(64 + srow) * 32 + sslot * 8];
  unsigned short* ldsB0 = &Bs[srow * 32 + sslot * 8];
  unsigned short* ldsB1 = &Bs[(64 + srow) * 32 + sslot * 8];

  f32x4 acc[4][4] = {};
  const int u   = lane >> 4;
  const int r15 = lane & 15;
  const int sw  = u ^ (r15 & 3);

  for (int ks = 0; ks < KSTEPS; ++ks) {
    const int k0 = ks * 32;
    __syncthreads();
    gload16(A + aBase0 + k0, ldsA0);
    gload16(A + aBase1 + k0, ldsA1);
    gload16(BT + bBase0 + k0, ldsB0);
    gload16(BT + bBase1 + k0, ldsB1);
    asm volatile("s_waitcnt vmcnt(0)" ::: "memory");
    __syncthreads();
    bf16x8 af[4], bfv[4];
#pragma unroll
    for (int m = 0; m < 4; ++m) {
      const int row = wm * 64 + m * 16 + r15;
      af[m]  = *(const bf16x8*)&As[row * 32 + sw * 8];
      const int col = wn * 64 + m * 16 + r15;
      bfv[m] = *(const bf16x8*)&Bs[col * 32 + sw * 8];
    }
#pragma unroll
    for (int m = 0; m < 4; ++m)
#pragma unroll
      for (int n = 0; n < 4; ++n)
        acc[m][n] = __builtin_amdgcn_mfma_f32_16x16x32_bf16(
            af[m], bfv[n], acc[m][n], 0, 0, 0);
  }
#pragma unroll
  for (int m = 0; m < 4; ++m) {
    const int r0 = brow + wm * 64 + m * 16 + u * 4;
#pragma unroll
    for (int n = 0; n < 4; ++n) {
      const int cc = bcol + wn * 64 + n * 16 + r15;
#pragma unroll
      for (int r = 0; r < 4; ++r)
        if (r0 + r < M) C[(size_t)(r0 + r) * Nn + cc] = f2b(acc[m][n][r]);
    }
  }
}

// ------------------------------------------------- per-node attention logits
template<int H, int C>
__global__ __launch_bounds__(H * C / 4)
void node_att(const unsigned short* __restrict__ h,
              const float* __restrict__ a_src, const float* __restrict__ a_dst,
              float* __restrict__ es, float* __restrict__ ed) {
  const int n = blockIdx.x;
  const int t = threadIdx.x;
  const int c4 = t * 4;
  const int head = c4 / C;
  const ushort4 hv = *(const ushort4*)&h[(size_t)n * (H * C) + c4];
  const float4 as = *(const float4*)&a_src[c4];
  const float4 ad = *(const float4*)&a_dst[c4];
  const float x0 = b2f(hv.x), x1 = b2f(hv.y), x2 = b2f(hv.z), x3 = b2f(hv.w);
  float ps = x0 * as.x + x1 * as.y + x2 * as.z + x3 * as.w;
  float pd = x0 * ad.x + x1 * ad.y + x2 * ad.z + x3 * ad.w;
#pragma unroll
  for (int off = C / 8; off >= 1; off >>= 1) {
    ps += __shfl_xor(ps, off);
    pd += __shfl_xor(pd, off);
  }
  if ((t & (C / 4 - 1)) == 0) {
    es[n * H + head] = ps;
    ed[n * H + head] = pd;
  }
}

// ---------------------- gather GAT aggregation + fused bias/LayerNorm(/ReLU)
// one wave per node; wave holds the full output row (64*F == H*C).
template<int H, int C, bool RELU, bool BFOUT>
__global__ __launch_bounds__(256)
void gat_agg_ln(const int* __restrict__ rowptr, const int* __restrict__ srcs,
                const unsigned short* __restrict__ h, const float* __restrict__ es,
                const float* __restrict__ ed, const float* __restrict__ bias,
                const float* __restrict__ lng, const float* __restrict__ lnb,
                unsigned short* __restrict__ obf, float* __restrict__ of32,
                int Nn) {
  constexpr int HC = H * C;
  constexpr int F  = HC / 64;          // 8 (layer1) or 4 (layer2)
  const int wave = threadIdx.x >> 6;
  const int lane = threadIdx.x & 63;
  const int n = blockIdx.x * 4 + wave;
  if (n >= Nn) return;
  const int beg = rowptr[n];
  const int deg = rowptr[n + 1] - beg;

  // pass 1: per-head softmax denominator
  const int myh = lane & (H - 1);
  const float edv = ed[n * H + myh];
  float ssum = 0.f;
  for (int it = lane; it < deg * H; it += 64) {
    const int j = (H == 4) ? (it >> 2) : it;
    const int src = srcs[beg + j];
    float e = es[src * H + myh] + edv;
    e = (e > 0.f) ? e : LRELU_SLOPE * e;
    ssum += __expf(e);
  }
#pragma unroll
  for (int off = H; off < 64; off <<= 1) ssum += __shfl_xor(ssum, off);

  const int hl = (lane * F) / C;
  const float s_mine = __shfl(ssum, hl) + 1e-16f;
  const float edh = ed[n * H + hl];

  // pass 2: gather + weighted accumulate (2-way unrolled)
  float acc[F];
#pragma unroll
  for (int i = 0; i < F; ++i) acc[i] = 0.f;

  auto fma_row = [&](int src, float alpha) {
    const unsigned short* hp = &h[(size_t)src * HC + lane * F];
    const ushort4 v0 = *(const ushort4*)hp;
    acc[0] = fmaf(b2f(v0.x), alpha, acc[0]);
    acc[1] = fmaf(b2f(v0.y), alpha, acc[1]);
    acc[2] = fmaf(b2f(v0.z), alpha, acc[2]);
    acc[3] = fmaf(b2f(v0.w), alpha, acc[3]);
    if constexpr (F == 8) {
      const ushort4 v1 = *(const ushort4*)(hp + 4);
      acc[4] = fmaf(b2f(v1.x), alpha, acc[4]);
      acc[5] = fmaf(b2f(v1.y), alpha, acc[5]);
      acc[6] = fmaf(b2f(v1.z), alpha, acc[6]);
      acc[7] = fmaf(b2f(v1.w), alpha, acc[7]);
    }
  };
  auto get_alpha = [&](int src) {
    float e = es[src * H + hl] + edh;
    e = (e > 0.f) ? e : LRELU_SLOPE * e;
    return __expf(e) / s_mine;
  };

  int j = 0;
  for (; j + 2 <= deg; j += 2) {
    const int s0 = srcs[beg + j], s1 = srcs[beg + j + 1];
    const float a0 = get_alpha(s0), a1 = get_alpha(s1);
    fma_row(s0, a0);
    fma_row(s1, a1);
  }
  if (j < deg) fma_row(srcs[beg + j], get_alpha(srcs[beg + j]));

  // fused bias + LayerNorm (+ReLU)
#pragma unroll
  for (int i = 0; i < F; i += 4) {
    const float4 bb = *(const float4*)&bias[lane * F + i];
    acc[i + 0] += bb.x; acc[i + 1] += bb.y;
    acc[i + 2] += bb.z; acc[i + 3] += bb.w;
  }
  float sum = 0.f, sq = 0.f;
#pragma unroll
  for (int i = 0; i < F; ++i) { sum += acc[i]; sq += acc[i] * acc[i]; }
#pragma unroll
  for (int off = 1; off < 64; off <<= 1) {
    sum += __shfl_xor(sum, off);
    sq  += __shfl_xor(sq, off);
  }
  const float mu  = sum / HC;
  const float var = sq / HC - mu * mu;
  const float r   = rsqrtf(var + 1e-5f);
  float y[F];
#pragma unroll
  for (int i = 0; i < F; i += 4) {
    const float4 gg = *(const float4*)&lng[lane * F + i];
    const float4 bl = *(const float4*)&lnb[lane * F + i];
    y[i + 0] = (acc[i + 0] - mu) * r * gg.x + bl.x;
    y[i + 1] = (acc[i + 1] - mu) * r * gg.y + bl.y;
    y[i + 2] = (acc[i + 2] - mu) * r * gg.z + bl.z;
    y[i + 3] = (acc[i + 3] - mu) * r * gg.w + bl.w;
  }
  if constexpr (RELU) {
#pragma unroll
    for (int i = 0; i < F; ++i) y[i] = fmaxf(y[i], 0.f);
  }
  if constexpr (BFOUT) {
    unsigned short* op = &obf[(size_t)n * HC + lane * F];
    *(ushort4*)op = make_ushort4(f2b(y[0]), f2b(y[1]), f2b(y[2]), f2b(y[3]));
    if constexpr (F == 8)
      *(ushort4*)(op + 4) = make_ushort4(f2b(y[4]), f2b(y[5]), f2b(y[6]), f2b(y[7]));
  } else {
    float* op = &of32[(size_t)n * HC + lane * F];
    *(float4*)op = make_float4(y[0], y[1], y[2], y[3]);
    if constexpr (F == 8)
      *(float4*)(op + 4) = make_float4(y[4], y[5], y[6], y[7]);
  }
}

// ---------------------------------------------------------- global mean pool
__global__ __launch_bounds__(256)
void pool_partial(const float* __restrict__ x, const int* __restrict__ batch,
                  float* __restrict__ tmp, int* __restrict__ cnt, int Nn) {
  const int r0 = blockIdx.x * 64;
  const int rend = min(r0 + 64, Nn);
  const int t = threadIdx.x;
  float acc = 0.f;
  int cur = batch[r0];
  int seglen = 0;
  for (int r = r0; r < rend; ++r) {
    const int g = batch[r];
    if (g != cur) {
      unsafeAtomicAdd(&tmp[cur * 256 + t], acc);
      if (t == 0) atomicAdd(&cnt[cur], seglen);
      acc = 0.f; seglen = 0; cur = g;
    }
    acc += x[(size_t)r * 256 + t];
    ++seglen;
  }
  unsafeAtomicAdd(&tmp[cur * 256 + t], acc);
  if (t == 0) atomicAdd(&cnt[cur], seglen);
}

__global__ __launch_bounds__(256)
void pool_final(const float* __restrict__ tmp, const int* __restrict__ cnt,
                float* __restrict__ out) {
  const int g = blockIdx.x;
  const int t = threadIdx.x;
  out[g * 256 + t] = tmp[g * 256 + t] / fmaxf((float)cnt[g], 1.f);
}

// ---------------------------------------------------------------------------
extern "C" void kernel_launch(void* const* d_in, const int* in_sizes, int n_in,
                              void* d_out, int out_size, void* d_ws, size_t ws_size,
                              hipStream_t stream) {
  const float* x    = (const float*)d_in[0];
  const int*   ei   = (const int*)d_in[1];
  const int*   batch= (const int*)d_in[2];
  const float* W1   = (const float*)d_in[3];
  const float* as1  = (const float*)d_in[4];
  const float* ad1  = (const float*)d_in[5];
  const float* b1   = (const float*)d_in[6];
  const float* g1   = (const float*)d_in[7];
  const float* be1  = (const float*)d_in[8];
  const float* W2   = (const float*)d_in[9];
  const float* as2  = (const float*)d_in[10];
  const float* ad2  = (const float*)d_in[11];
  const float* b2   = (const float*)d_in[12];
  const float* g2   = (const float*)d_in[13];
  const float* be2  = (const float*)d_in[14];

  const int N    = in_sizes[0] / 256;   // 50000
  const int E    = in_sizes[1] / 2;     // 400000
  const int Etot = E + N;
  const int Mpad = ((N + 127) / 128) * 128;   // 50048
  const int NB   = (N + 1023) / 1024;         // scan blocks (49)

  // ---------------- workspace layout ----------------
  float* ws = (float*)d_ws;
  float* out2 = ws;                                    // N*256 f32
  unsigned short* A2bf = (unsigned short*)(out2 + (size_t)N * 256); // Mpad*512 bf16
  unsigned short* A1bf = A2bf;                         // Mpad*256 bf16 (dead before gat_agg_ln1 writes)
  unsigned short* h1bf = A2bf + (size_t)Mpad * 512;    // N*512 bf16 (h2bf aliases)
  unsigned short* W1T  = h1bf + (size_t)N * 512;       // 512*256 bf16
  unsigned short* W2T  = W1T + 512 * 256;              // 256*512 bf16
  float* es   = (float*)(W2T + 512 * 256);             // N*4
  float* ed   = es + (size_t)N * 4;                    // N*4
  int* count  = (int*)(ed + (size_t)N * 4);            // N
  int* rowptr = count + N;                             // N+1
  int* cursor = rowptr + N + 1;                        // N
  int* srcs   = cursor + N;                            // Etot
  float* ptmp = (float*)(srcs + Etot);                 // 64*256
  int*   pcnt = (int*)(ptmp + 64 * 256);               // 64
  int*   bsum = pcnt + 64;                             // NB
  int*   boff = bsum + 64;                             // NB
  unsigned short* h2bf = h1bf;

  const int eb = (Etot + 255) / 256;

  // ---- zero-init via async memset (count, pool accum, A2 pad rows) ----
  hipMemsetAsync(count, 0, (size_t)N * 4, stream);
  hipMemsetAsync(ptmp, 0, (size_t)(64 * 256 + 64) * 4, stream);
  hipMemsetAsync(A2bf + (size_t)N * 512, 0, (size_t)(Mpad - N) * 512 * 2, stream);

  // ---- CSR build ----
  csr_count<<<eb, 256, 0, stream>>>(ei, E, Etot, count);
  scan_blocksum<<<NB, 256, 0, stream>>>(count, bsum, N);
  scan_top<<<1, 64, 0, stream>>>(bsum, boff, &rowptr[N], NB);
  scan_apply<<<NB, 256, 0, stream>>>(count, boff, rowptr, cursor, N);
  csr_scatter<<<eb, 256, 0, stream>>>(ei, E, Etot, cursor, srcs);

  // ---- operand conversion ----
  cvt_bf16_pad<<<((size_t)Mpad * 64 + 255) / 256, 256, 0, stream>>>(x, A1bf, N, 256, Mpad);
  cvt_wt<<<(512 * 256 + 255) / 256, 256, 0, stream>>>(W1, W1T, 256, 512);
  cvt_wt<<<(512 * 256 + 255) / 256, 256, 0, stream>>>(W2, W2T, 512, 256);

  // ---- layer 1: GATConv(256 -> 4x128) + LN + ReLU ----
  gemm_bf16<8><<<dim3(4, Mpad / 128), 256, 0, stream>>>(A1bf, W1T, h1bf, N, 512, 256);
  node_att<4, 128><<<N, 128, 0, stream>>>(h1bf, as1, ad1, es, ed);
  gat_agg_ln<4, 128, true, true><<<(N + 3) / 4, 256, 0, stream>>>(
      rowptr, srcs, h1bf, es, ed, b1, g1, be1, A2bf, nullptr, N);

  // ---- layer 2: GATConv(512 -> 1x256) + LN ----
  gemm_bf16<16><<<dim3(2, Mpad / 128), 256, 0, stream>>>(A2bf, W2T, h2bf, N, 256, 512);
  node_att<1, 256><<<N, 64, 0, stream>>>(h2bf, as2, ad2, es, ed);
  gat_agg_ln<1, 256, false, false><<<(N + 3) / 4, 256, 0, stream>>>(
      rowptr, srcs, h2bf, es, ed, b2, g2, be2, nullptr, out2, N);

  // ---- global mean pool ----
  pool_partial<<<(N + 63) / 64, 256, 0, stream>>>(out2, batch, ptmp, pcnt, N);
  pool_final<<<64, 256, 0, stream>>>(ptmp, pcnt, (float*)d_out);
}

// Round 5
// 318.479 us; speedup vs baseline: 16.0439x; 1.0136x over previous
//
#include <hip/hip_runtime.h>
#include <hip/hip_bf16.h>
#include <cstdint>

#define LRELU_SLOPE 0.2f

typedef short bf16x8 __attribute__((ext_vector_type(8)));
typedef float f32x4  __attribute__((ext_vector_type(4)));

__device__ __forceinline__ float b2f(unsigned short u) {
  return __uint_as_float(((unsigned int)u) << 16);
}
__device__ __forceinline__ unsigned short f2b(float f) {  // RNE
  unsigned int u = __float_as_uint(f);
  return (unsigned short)((u + 0x7fff + ((u >> 16) & 1)) >> 16);
}

__device__ __forceinline__ void gload16(const void* g, void* l) {
  __builtin_amdgcn_global_load_lds(
      (const __attribute__((address_space(1))) unsigned int*)g,
      (__attribute__((address_space(3))) unsigned int*)l, 16, 0, 0);
}

// ------------------------------------------------------------------- convert
__global__ __launch_bounds__(256)
void cvt_bf16_pad(const float* __restrict__ x, unsigned short* __restrict__ o,
                  int M, int D, int Mpad) {
  const int i = blockIdx.x * 256 + threadIdx.x;
  const int per_row = D / 4;
  if (i >= Mpad * per_row) return;
  const int row = i / per_row;
  const int c4  = (i % per_row) * 4;
  ushort4 v = make_ushort4(0, 0, 0, 0);
  if (row < M) {
    const float4 f = *(const float4*)&x[(size_t)row * D + c4];
    v = make_ushort4(f2b(f.x), f2b(f.y), f2b(f.z), f2b(f.w));
  }
  *(ushort4*)&o[(size_t)row * D + c4] = v;
}

__global__ __launch_bounds__(256)
void cvt_wt(const float* __restrict__ W, unsigned short* __restrict__ WT,
            int K, int N) {
  const int j = blockIdx.x * 256 + threadIdx.x;
  if (j >= N * K) return;
  const int n = j / K, k = j % K;
  WT[j] = f2b(W[(size_t)k * N + n]);
}

// ------------------------------------------------------------- CSR building
__global__ __launch_bounds__(256)
void csr_count(const int* __restrict__ ei, int E, int Etot,
               int* __restrict__ count) {
  const int i = blockIdx.x * 256 + threadIdx.x;
  if (i >= Etot) return;
  const int d = (i < E) ? ei[E + i] : (i - E);
  atomicAdd(&count[d], 1);
}

__global__ __launch_bounds__(256)
void scan_blocksum(const int* __restrict__ count, int* __restrict__ bsum, int Nn) {
  const int i0 = blockIdx.x * 1024 + threadIdx.x * 4;
  int s = 0;
#pragma unroll
  for (int k = 0; k < 4; ++k) { const int i = i0 + k; if (i < Nn) s += count[i]; }
#pragma unroll
  for (int off = 1; off < 64; off <<= 1) s += __shfl_xor(s, off);
  __shared__ int ws[4];
  if ((threadIdx.x & 63) == 0) ws[threadIdx.x >> 6] = s;
  __syncthreads();
  if (threadIdx.x == 0) bsum[blockIdx.x] = ws[0] + ws[1] + ws[2] + ws[3];
}

__global__ __launch_bounds__(64)
void scan_top(const int* __restrict__ bsum, int* __restrict__ boff,
              int* __restrict__ rowptrN, int nb) {
  const int t = threadIdx.x;
  const int v = (t < nb) ? bsum[t] : 0;
  int incl = v;
#pragma unroll
  for (int off = 1; off < 64; off <<= 1) {
    const int u = __shfl_up(incl, off);
    if (t >= off) incl += u;
  }
  if (t < nb) boff[t] = incl - v;
  if (t == 63) *rowptrN = incl;
}

__global__ __launch_bounds__(256)
void scan_apply(const int* __restrict__ count, const int* __restrict__ boff,
                int* __restrict__ rowptr, int* __restrict__ cursor, int Nn) {
  const int t = threadIdx.x;
  const int lane = t & 63;
  const int w = t >> 6;
  const int i0 = blockIdx.x * 1024 + t * 4;
  int c[4]; int s = 0;
#pragma unroll
  for (int k = 0; k < 4; ++k) { const int i = i0 + k; c[k] = (i < Nn) ? count[i] : 0; s += c[k]; }
  int incl = s;
#pragma unroll
  for (int off = 1; off < 64; off <<= 1) {
    const int u = __shfl_up(incl, off);
    if (lane >= off) incl += u;
  }
  __shared__ int ws[4];
  if (lane == 63) ws[w] = incl;
  __syncthreads();
  int woff = 0;
  for (int k = 0; k < w; ++k) woff += ws[k];
  int base = boff[blockIdx.x] + woff + incl - s;
#pragma unroll
  for (int k = 0; k < 4; ++k) {
    const int i = i0 + k;
    if (i < Nn) { rowptr[i] = base; cursor[i] = base; base += c[k]; }
  }
}

__global__ __launch_bounds__(256)
void csr_scatter(const int* __restrict__ ei, int E, int Etot,
                 int* __restrict__ cursor, int* __restrict__ srcs) {
  const int i = blockIdx.x * 256 + threadIdx.x;
  if (i >= Etot) return;
  const int s = (i < E) ? ei[i]     : (i - E);
  const int d = (i < E) ? ei[E + i] : (i - E);
  const int pos = atomicAdd(&cursor[d], 1);
  srcs[pos] = s;
}

// ------------------------------------------- bf16 MFMA GEMM, double-buffered
// C[M,N](bf16) = A[Mpad,K](bf16) @ BT[N,K](bf16)^T.  128x128 tile, BK=32,
// 2-phase pipeline: stage(t+1) issued before compute(t), one barrier/step.
template<int KSTEPS>
__global__ __launch_bounds__(256)
void gemm_bf16(const unsigned short* __restrict__ A,
               const unsigned short* __restrict__ BT,
               unsigned short* __restrict__ C, int M, int Nn, int K) {
  __shared__ unsigned short As[2][128 * 32];
  __shared__ unsigned short Bs[2][128 * 32];
  const int tid  = threadIdx.x;
  const int lane = tid & 63;
  const int wave = tid >> 6;
  const int wm = wave >> 1, wn = wave & 1;
  const int brow = blockIdx.y * 128;
  const int bcol = blockIdx.x * 128;
  const int srow  = tid >> 2;
  const int sslot = tid & 3;
  const int sswz  = sslot ^ (srow & 3);
  const size_t aBase0 = (size_t)(brow + srow) * K + sswz * 8;
  const size_t aBase1 = (size_t)(brow + 64 + srow) * K + sswz * 8;
  const size_t bBase0 = (size_t)(bcol + srow) * K + sswz * 8;
  const size_t bBase1 = (size_t)(bcol + 64 + srow) * K + sswz * 8;
  const int ldsOff0 = srow * 32 + sslot * 8;
  const int ldsOff1 = (64 + srow) * 32 + sslot * 8;

  f32x4 acc[4][4] = {};
  const int u   = lane >> 4;
  const int r15 = lane & 15;
  const int sw  = u ^ (r15 & 3);

  auto stage = [&](int buf, int ks) {
    const int k0 = ks * 32;
    gload16(A + aBase0 + k0, &As[buf][ldsOff0]);
    gload16(A + aBase1 + k0, &As[buf][ldsOff1]);
    gload16(BT + bBase0 + k0, &Bs[buf][ldsOff0]);
    gload16(BT + bBase1 + k0, &Bs[buf][ldsOff1]);
  };

  stage(0, 0);
  asm volatile("s_waitcnt vmcnt(0)" ::: "memory");
  __syncthreads();
  int cur = 0;
#pragma unroll
  for (int ks = 0; ks < KSTEPS; ++ks) {
    if (ks + 1 < KSTEPS) stage(cur ^ 1, ks + 1);
    bf16x8 af[4], bfv[4];
#pragma unroll
    for (int m = 0; m < 4; ++m) {
      const int row = wm * 64 + m * 16 + r15;
      af[m]  = *(const bf16x8*)&As[cur][row * 32 + sw * 8];
      const int col = wn * 64 + m * 16 + r15;
      bfv[m] = *(const bf16x8*)&Bs[cur][col * 32 + sw * 8];
    }
#pragma unroll
    for (int m = 0; m < 4; ++m)
#pragma unroll
      for (int n = 0; n < 4; ++n)
        acc[m][n] = __builtin_amdgcn_mfma_f32_16x16x32_bf16(
            af[m], bfv[n], acc[m][n], 0, 0, 0);
    if (ks + 1 < KSTEPS) {
      asm volatile("s_waitcnt vmcnt(0)" ::: "memory");
      __syncthreads();
      cur ^= 1;
    }
  }
#pragma unroll
  for (int m = 0; m < 4; ++m) {
    const int r0 = brow + wm * 64 + m * 16 + u * 4;
#pragma unroll
    for (int n = 0; n < 4; ++n) {
      const int cc = bcol + wn * 64 + n * 16 + r15;
#pragma unroll
      for (int r = 0; r < 4; ++r)
        if (r0 + r < M) C[(size_t)(r0 + r) * Nn + cc] = f2b(acc[m][n][r]);
    }
  }
}

// ------------------------------------------------- per-node attention logits
template<int H, int C>
__global__ __launch_bounds__(H * C / 4)
void node_att(const unsigned short* __restrict__ h,
              const float* __restrict__ a_src, const float* __restrict__ a_dst,
              float* __restrict__ es, float* __restrict__ ed) {
  const int n = blockIdx.x;
  const int t = threadIdx.x;
  const int c4 = t * 4;
  const int head = c4 / C;
  const ushort4 hv = *(const ushort4*)&h[(size_t)n * (H * C) + c4];
  const float4 as = *(const float4*)&a_src[c4];
  const float4 ad = *(const float4*)&a_dst[c4];
  const float x0 = b2f(hv.x), x1 = b2f(hv.y), x2 = b2f(hv.z), x3 = b2f(hv.w);
  float ps = x0 * as.x + x1 * as.y + x2 * as.z + x3 * as.w;
  float pd = x0 * ad.x + x1 * ad.y + x2 * ad.z + x3 * ad.w;
#pragma unroll
  for (int off = C / 8; off >= 1; off >>= 1) {
    ps += __shfl_xor(ps, off);
    pd += __shfl_xor(pd, off);
  }
  if ((t & (C / 4 - 1)) == 0) {
    es[n * H + head] = ps;
    ed[n * H + head] = pd;
  }
}

// ---------------------- gather GAT aggregation + fused bias/LayerNorm(/ReLU)
// one wave per node; 4-deep gather pipeline; inv_s multiply.
template<int H, int C, bool RELU, bool BFOUT>
__global__ __launch_bounds__(256)
void gat_agg_ln(const int* __restrict__ rowptr, const int* __restrict__ srcs,
                const unsigned short* __restrict__ h, const float* __restrict__ es,
                const float* __restrict__ ed, const float* __restrict__ bias,
                const float* __restrict__ lng, const float* __restrict__ lnb,
                unsigned short* __restrict__ obf, float* __restrict__ of32,
                int Nn) {
  constexpr int HC = H * C;
  constexpr int F  = HC / 64;          // 8 (layer1) or 4 (layer2)
  const int wave = threadIdx.x >> 6;
  const int lane = threadIdx.x & 63;
  const int n = blockIdx.x * 4 + wave;
  if (n >= Nn) return;
  const int beg = rowptr[n];
  const int deg = rowptr[n + 1] - beg;

  // pass 1: per-head softmax denominator
  const int myh = lane & (H - 1);
  const float edv = ed[n * H + myh];
  float ssum = 0.f;
  for (int it = lane; it < deg * H; it += 64) {
    const int j = (H == 4) ? (it >> 2) : it;
    const int src = srcs[beg + j];
    float e = es[src * H + myh] + edv;
    e = (e > 0.f) ? e : LRELU_SLOPE * e;
    ssum += __expf(e);
  }
#pragma unroll
  for (int off = H; off < 64; off <<= 1) ssum += __shfl_xor(ssum, off);

  const int hl = (lane * F) / C;
  const float inv_s = 1.0f / (__shfl(ssum, hl) + 1e-16f);
  const float edh = ed[n * H + hl];

  float acc[F];
#pragma unroll
  for (int i = 0; i < F; ++i) acc[i] = 0.f;

  auto get_alpha = [&](int src) {
    float e = es[src * H + hl] + edh;
    e = (e > 0.f) ? e : LRELU_SLOPE * e;
    return __expf(e) * inv_s;
  };
  auto fma_rows = [&](const ushort4* v0, const ushort4* v1, const float* a, int cnt) {
    for (int q = 0; q < cnt; ++q) {
      acc[0] = fmaf(b2f(v0[q].x), a[q], acc[0]);
      acc[1] = fmaf(b2f(v0[q].y), a[q], acc[1]);
      acc[2] = fmaf(b2f(v0[q].z), a[q], acc[2]);
      acc[3] = fmaf(b2f(v0[q].w), a[q], acc[3]);
      if constexpr (F == 8) {
        acc[4] = fmaf(b2f(v1[q].x), a[q], acc[4]);
        acc[5] = fmaf(b2f(v1[q].y), a[q], acc[5]);
        acc[6] = fmaf(b2f(v1[q].z), a[q], acc[6]);
        acc[7] = fmaf(b2f(v1[q].w), a[q], acc[7]);
      }
    }
  };

  // pass 2: 4-deep gather pipeline — issue 4 row loads, then 4 alpha FMAs.
  int j = 0;
  for (; j + 4 <= deg; j += 4) {
    int s4[4];
#pragma unroll
    for (int q = 0; q < 4; ++q) s4[q] = srcs[beg + j + q];
    ushort4 v0[4], v1[4];
#pragma unroll
    for (int q = 0; q < 4; ++q) {
      const unsigned short* hp = &h[(size_t)s4[q] * HC + lane * F];
      v0[q] = *(const ushort4*)hp;
      if constexpr (F == 8) v1[q] = *(const ushort4*)(hp + 4);
    }
    float a4[4];
#pragma unroll
    for (int q = 0; q < 4; ++q) a4[q] = get_alpha(s4[q]);
    fma_rows(v0, v1, a4, 4);
  }
  for (; j < deg; ++j) {
    const int src = srcs[beg + j];
    const unsigned short* hp = &h[(size_t)src * HC + lane * F];
    ushort4 v0 = *(const ushort4*)hp, v1;
    if constexpr (F == 8) v1 = *(const ushort4*)(hp + 4);
    const float a = get_alpha(src);
    fma_rows(&v0, &v1, &a, 1);
  }

  // fused bias + LayerNorm (+ReLU)
#pragma unroll
  for (int i = 0; i < F; i += 4) {
    const float4 bb = *(const float4*)&bias[lane * F + i];
    acc[i + 0] += bb.x; acc[i + 1] += bb.y;
    acc[i + 2] += bb.z; acc[i + 3] += bb.w;
  }
  float sum = 0.f, sq = 0.f;
#pragma unroll
  for (int i = 0; i < F; ++i) { sum += acc[i]; sq += acc[i] * acc[i]; }
#pragma unroll
  for (int off = 1; off < 64; off <<= 1) {
    sum += __shfl_xor(sum, off);
    sq  += __shfl_xor(sq, off);
  }
  const float mu  = sum / HC;
  const float var = sq / HC - mu * mu;
  const float r   = rsqrtf(var + 1e-5f);
  float y[F];
#pragma unroll
  for (int i = 0; i < F; i += 4) {
    const float4 gg = *(const float4*)&lng[lane * F + i];
    const float4 bl = *(const float4*)&lnb[lane * F + i];
    y[i + 0] = (acc[i + 0] - mu) * r * gg.x + bl.x;
    y[i + 1] = (acc[i + 1] - mu) * r * gg.y + bl.y;
    y[i + 2] = (acc[i + 2] - mu) * r * gg.z + bl.z;
    y[i + 3] = (acc[i + 3] - mu) * r * gg.w + bl.w;
  }
  if constexpr (RELU) {
#pragma unroll
    for (int i = 0; i < F; ++i) y[i] = fmaxf(y[i], 0.f);
  }
  if constexpr (BFOUT) {
    unsigned short* op = &obf[(size_t)n * HC + lane * F];
    *(ushort4*)op = make_ushort4(f2b(y[0]), f2b(y[1]), f2b(y[2]), f2b(y[3]));
    if constexpr (F == 8)
      *(ushort4*)(op + 4) = make_ushort4(f2b(y[4]), f2b(y[5]), f2b(y[6]), f2b(y[7]));
  } else {
    float* op = &of32[(size_t)n * HC + lane * F];
    *(float4*)op = make_float4(y[0], y[1], y[2], y[3]);
    if constexpr (F == 8)
      *(float4*)(op + 4) = make_float4(y[4], y[5], y[6], y[7]);
  }
}

// ---------------------------------------------------------- global mean pool
__global__ __launch_bounds__(256)
void pool_partial(const unsigned short* __restrict__ x, const int* __restrict__ batch,
                  float* __restrict__ tmp, int* __restrict__ cnt, int Nn) {
  const int r0 = blockIdx.x * 64;
  const int rend = min(r0 + 64, Nn);
  const int t = threadIdx.x;
  float acc = 0.f;
  int cur = batch[r0];
  int seglen = 0;
  for (int r = r0; r < rend; ++r) {
    const int g = batch[r];
    if (g != cur) {
      unsafeAtomicAdd(&tmp[cur * 256 + t], acc);
      if (t == 0) atomicAdd(&cnt[cur], seglen);
      acc = 0.f; seglen = 0; cur = g;
    }
    acc += b2f(x[(size_t)r * 256 + t]);
    ++seglen;
  }
  unsafeAtomicAdd(&tmp[cur * 256 + t], acc);
  if (t == 0) atomicAdd(&cnt[cur], seglen);
}

__global__ __launch_bounds__(256)
void pool_final(const float* __restrict__ tmp, const int* __restrict__ cnt,
                float* __restrict__ out) {
  const int g = blockIdx.x;
  const int t = threadIdx.x;
  out[g * 256 + t] = tmp[g * 256 + t] / fmaxf((float)cnt[g], 1.f);
}

// ---------------------------------------------------------------------------
extern "C" void kernel_launch(void* const* d_in, const int* in_sizes, int n_in,
                              void* d_out, int out_size, void* d_ws, size_t ws_size,
                              hipStream_t stream) {
  const float* x    = (const float*)d_in[0];
  const int*   ei   = (const int*)d_in[1];
  const int*   batch= (const int*)d_in[2];
  const float* W1   = (const float*)d_in[3];
  const float* as1  = (const float*)d_in[4];
  const float* ad1  = (const float*)d_in[5];
  const float* b1   = (const float*)d_in[6];
  const float* g1   = (const float*)d_in[7];
  const float* be1  = (const float*)d_in[8];
  const float* W2   = (const float*)d_in[9];
  const float* as2  = (const float*)d_in[10];
  const float* ad2  = (const float*)d_in[11];
  const float* b2   = (const float*)d_in[12];
  const float* g2   = (const float*)d_in[13];
  const float* be2  = (const float*)d_in[14];

  const int N    = in_sizes[0] / 256;   // 50000
  const int E    = in_sizes[1] / 2;     // 400000
  const int Etot = E + N;
  const int Mpad = ((N + 127) / 128) * 128;   // 50048
  const int NB   = (N + 1023) / 1024;         // scan blocks (49)

  // ---------------- workspace layout ----------------
  float* ws = (float*)d_ws;
  unsigned short* out2 = (unsigned short*)ws;          // N*256 bf16
  unsigned short* A2bf = out2 + (size_t)N * 256;       // Mpad*512 bf16
  unsigned short* A1bf = A2bf;                         // Mpad*256 bf16 (dead before agg1 writes)
  unsigned short* h1bf = A2bf + (size_t)Mpad * 512;    // N*512 bf16 (h2bf aliases)
  unsigned short* W1T  = h1bf + (size_t)N * 512;       // 512*256 bf16
  unsigned short* W2T  = W1T + 512 * 256;              // 256*512 bf16
  float* es   = (float*)(W2T + 512 * 256);             // N*4
  float* ed   = es + (size_t)N * 4;                    // N*4
  int* count  = (int*)(ed + (size_t)N * 4);            // N
  int* rowptr = count + N;                             // N+1
  int* cursor = rowptr + N + 1;                        // N
  int* srcs   = cursor + N;                            // Etot
  float* ptmp = (float*)(srcs + Etot);                 // 64*256
  int*   pcnt = (int*)(ptmp + 64 * 256);               // 64
  int*   bsum = pcnt + 64;                             // NB
  int*   boff = bsum + 64;                             // NB
  unsigned short* h2bf = h1bf;

  const int eb = (Etot + 255) / 256;

  // ---- zero-init ----
  hipMemsetAsync(count, 0, (size_t)N * 4, stream);
  hipMemsetAsync(ptmp, 0, (size_t)(64 * 256 + 64) * 4, stream);
  hipMemsetAsync(A2bf + (size_t)N * 512, 0, (size_t)(Mpad - N) * 512 * 2, stream);

  // ---- CSR build ----
  csr_count<<<eb, 256, 0, stream>>>(ei, E, Etot, count);
  scan_blocksum<<<NB, 256, 0, stream>>>(count, bsum, N);
  scan_top<<<1, 64, 0, stream>>>(bsum, boff, &rowptr[N], NB);
  scan_apply<<<NB, 256, 0, stream>>>(count, boff, rowptr, cursor, N);
  csr_scatter<<<eb, 256, 0, stream>>>(ei, E, Etot, cursor, srcs);

  // ---- operand conversion ----
  cvt_bf16_pad<<<((size_t)Mpad * 64 + 255) / 256, 256, 0, stream>>>(x, A1bf, N, 256, Mpad);
  cvt_wt<<<(512 * 256 + 255) / 256, 256, 0, stream>>>(W1, W1T, 256, 512);
  cvt_wt<<<(512 * 256 + 255) / 256, 256, 0, stream>>>(W2, W2T, 512, 256);

  // ---- layer 1: GATConv(256 -> 4x128) + LN + ReLU ----
  gemm_bf16<8><<<dim3(4, Mpad / 128), 256, 0, stream>>>(A1bf, W1T, h1bf, N, 512, 256);
  node_att<4, 128><<<N, 128, 0, stream>>>(h1bf, as1, ad1, es, ed);
  gat_agg_ln<4, 128, true, true><<<(N + 3) / 4, 256, 0, stream>>>(
      rowptr, srcs, h1bf, es, ed, b1, g1, be1, A2bf, nullptr, N);

  // ---- layer 2: GATConv(512 -> 1x256) + LN ----
  gemm_bf16<16><<<dim3(2, Mpad / 128), 256, 0, stream>>>(A2bf, W2T, h2bf, N, 256, 512);
  node_att<1, 256><<<N, 64, 0, stream>>>(h2bf, as2, ad2, es, ed);
  gat_agg_ln<1, 256, false, true><<<(N + 3) / 4, 256, 0, stream>>>(
      rowptr, srcs, h2bf, es, ed, b2, g2, be2, out2, nullptr, N);

  // ---- global mean pool ----
  pool_partial<<<(N + 63) / 64, 256, 0, stream>>>(out2, batch, ptmp, pcnt, N);
  pool_final<<<64, 256, 0, stream>>>(ptmp, pcnt, (float*)d_out);
}